// Round 1
// baseline (393.058 us; speedup 1.0000x reference)
//
#include <hip/hip_runtime.h>

#define BS 512
#define NN 128
#define HEADS 8
#define DIN 64
#define DOUT 64

// one block per (b, head); 256 threads = 4 waves
__global__ __launch_bounds__(256) void gat_fwd(
    const float* __restrict__ hin,    // [BS][NN][DIN]
    const int*   __restrict__ adj,    // [BS][NN][NN] (0/1)
    const float* __restrict__ w,      // [HEADS][DIN][DOUT]
    const float* __restrict__ a_src,  // [HEADS][DOUT]
    const float* __restrict__ a_dst,  // [HEADS][DOUT]
    const float* __restrict__ bias,   // [DOUT]
    float* __restrict__ out)          // [BS][HEADS][NN][DOUT]
{
    __shared__ float hp[NN][DOUT];        // 32 KB  h_prime for this (b,h)
    __shared__ float s_src[NN];
    __shared__ float s_dst[NN];
    __shared__ float p_buf[4][8][NN];     // 16 KB  softmax rows per wave

    const int bh   = blockIdx.x;
    const int b    = bh >> 3;
    const int hd   = bh & 7;
    const int tid  = threadIdx.x;
    const int lane = tid & 63;
    const int wave = tid >> 6;

    // hoist w column for my output channel o = lane
    float wreg[DIN];
    #pragma unroll
    for (int i = 0; i < DIN; ++i)
        wreg[i] = w[(hd * DIN + i) * DOUT + lane];
    const float asr = a_src[hd * DOUT + lane];
    const float adr = a_dst[hd * DOUT + lane];

    // ---- GEMM1: hp[n][o] = sum_i h[b,n,i] * w[h,i,o];  + attn_src/dst ----
    const float* hb = hin + (size_t)b * NN * DIN;
    for (int k = 0; k < 32; ++k) {
        const int n = wave * 32 + k;
        const float4* hrow = reinterpret_cast<const float4*>(hb + n * DIN);
        float acc = 0.f;
        #pragma unroll
        for (int i4 = 0; i4 < DIN / 4; ++i4) {
            float4 hv = hrow[i4];   // uniform-address broadcast load
            acc = fmaf(hv.x, wreg[4 * i4 + 0], acc);
            acc = fmaf(hv.y, wreg[4 * i4 + 1], acc);
            acc = fmaf(hv.z, wreg[4 * i4 + 2], acc);
            acc = fmaf(hv.w, wreg[4 * i4 + 3], acc);
        }
        hp[n][lane] = acc;
        // tanh via exp (robust at +/- large: 1 - 2/(e^{2x}+1))
        const float ex = __expf(2.f * acc);
        const float t  = 1.f - 2.f / (ex + 1.f);
        float vs = t * asr;
        float vd = t * adr;
        #pragma unroll
        for (int m = 32; m >= 1; m >>= 1) {
            vs += __shfl_xor(vs, m);
            vd += __shfl_xor(vd, m);
        }
        if (lane == 0) { s_src[n] = vs; s_dst[n] = vd; }
    }
    __syncthreads();

    // ---- softmax rows + GEMM2, 8 rows per wave-batch ----
    const int*  adjb = adj + (size_t)b * NN * NN;
    float*      outb = out + (size_t)bh * NN * DOUT;
    const float bo   = bias[lane];
    const float d1   = s_dst[lane];
    const float d2   = s_dst[lane + 64];

    for (int batch = 0; batch < 4; ++batch) {
        const int i0 = wave * 32 + batch * 8;
        // softmax for 8 rows -> p_buf
        #pragma unroll
        for (int r = 0; r < 8; ++r) {
            const int i  = i0 + r;
            const float si = s_src[i];
            const int m1 = adjb[i * NN + lane];
            const int m2 = adjb[i * NN + lane + 64];
            float x1 = si + d1;  x1 = x1 > 0.f ? x1 : 0.2f * x1;
            float x2 = si + d2;  x2 = x2 > 0.f ? x2 : 0.2f * x2;
            float mx = fmaxf(m1 ? x1 : -3.0e38f, m2 ? x2 : -3.0e38f);
            #pragma unroll
            for (int m = 32; m >= 1; m >>= 1) mx = fmaxf(mx, __shfl_xor(mx, m));
            const float e1 = m1 ? __expf(x1 - mx) : 0.f;
            const float e2 = m2 ? __expf(x2 - mx) : 0.f;
            float sum = e1 + e2;
            #pragma unroll
            for (int m = 32; m >= 1; m >>= 1) sum += __shfl_xor(sum, m);
            const float inv = 1.f / sum;
            p_buf[wave][r][lane]      = e1 * inv;
            p_buf[wave][r][lane + 64] = e2 * inv;
        }
        // GEMM2: out[i][o] = sum_j p[i][j] * hp[j][o], 8 rows at once
        float acc[8];
        #pragma unroll
        for (int r = 0; r < 8; ++r) acc[r] = 0.f;
        for (int j4 = 0; j4 < NN / 4; ++j4) {
            const float hv0 = hp[4 * j4 + 0][lane];
            const float hv1 = hp[4 * j4 + 1][lane];
            const float hv2 = hp[4 * j4 + 2][lane];
            const float hv3 = hp[4 * j4 + 3][lane];
            #pragma unroll
            for (int r = 0; r < 8; ++r) {
                const float4 pv = *reinterpret_cast<const float4*>(&p_buf[wave][r][4 * j4]);
                acc[r] = fmaf(pv.x, hv0,
                         fmaf(pv.y, hv1,
                         fmaf(pv.z, hv2,
                         fmaf(pv.w, hv3, acc[r]))));
            }
        }
        #pragma unroll
        for (int r = 0; r < 8; ++r)
            outb[(i0 + r) * DOUT + lane] = acc[r] + bo;
    }
}

extern "C" void kernel_launch(void* const* d_in, const int* in_sizes, int n_in,
                              void* d_out, int out_size, void* d_ws, size_t ws_size,
                              hipStream_t stream) {
    const float* h     = (const float*)d_in[0];
    const int*   adj   = (const int*)d_in[1];
    const float* w     = (const float*)d_in[2];
    const float* a_src = (const float*)d_in[3];
    const float* a_dst = (const float*)d_in[4];
    const float* bias  = (const float*)d_in[5];
    float* out = (float*)d_out;
    gat_fwd<<<dim3(BS * HEADS), dim3(256), 0, stream>>>(h, adj, w, a_src, a_dst, bias, out);
}

// Round 2
// 76.222 us; speedup vs baseline: 5.1567x; 5.1567x over previous
//
#include <hip/hip_runtime.h>

#define BSZ 512
#define NN 128
#define HEADS 8
#define DIN 64
#define DOUT 64

typedef __bf16 bf16x8 __attribute__((ext_vector_type(8)));
typedef float floatx4 __attribute__((ext_vector_type(4)));

static __device__ __forceinline__ unsigned short f2bf(float f) {
    __bf16 b = (__bf16)f;
    return __builtin_bit_cast(unsigned short, b);
}
static __device__ __forceinline__ bf16x8 ld_frag(const unsigned short* p) {
    uint4 r = *reinterpret_cast<const uint4*>(p);
    return __builtin_bit_cast(bf16x8, r);
}

// one block per batch element b; 512 threads = 8 waves
__global__ __launch_bounds__(512, 4) void gat_fwd(
    const float* __restrict__ hin,    // [BSZ][NN][DIN]
    const int*   __restrict__ adj,    // [BSZ][NN][NN]
    const float* __restrict__ w,      // [HEADS][DIN][DOUT]
    const float* __restrict__ a_src,  // [HEADS][DOUT]
    const float* __restrict__ a_dst,  // [HEADS][DOUT]
    const float* __restrict__ bias,   // [DOUT]
    float* __restrict__ out)          // [BSZ][HEADS][NN][DOUT]
{
    // all tiles XOR-swizzled: elem_idx ^= (row&7)<<3  (16B chunk swizzle)
    __shared__ __attribute__((aligned(16))) unsigned short h_lds[NN * DIN];   // [n][k] bf16
    __shared__ __attribute__((aligned(16))) unsigned short wT[DOUT * DIN];    // [o][k] bf16
    __shared__ __attribute__((aligned(16))) unsigned short hpT[DOUT * NN];    // [o][j] bf16
    __shared__ __attribute__((aligned(16))) unsigned int   msk[NN * 4];       // row bitmasks
    __shared__ __attribute__((aligned(16))) float s_src[NN];
    __shared__ __attribute__((aligned(16))) float s_dst[NN];

    const int b    = blockIdx.x;
    const int tid  = threadIdx.x;
    const int lane = tid & 63;
    const int wv   = tid >> 6;    // 0..7
    const int lg   = lane >> 4;   // 0..3
    const int lm   = lane & 15;   // 0..15

    // ---- stage h (fp32 -> bf16, swizzled) ----
    const float* hb = hin + (size_t)b * NN * DIN;
    #pragma unroll
    for (int q = 0; q < 4; ++q) {
        const int flat = q * 2048 + tid * 4;
        const int n = flat >> 6, k = flat & 63;
        float4 v = *reinterpret_cast<const float4*>(hb + flat);
        unsigned int lo = f2bf(v.x) | ((unsigned int)f2bf(v.y) << 16);
        unsigned int hi = f2bf(v.z) | ((unsigned int)f2bf(v.w) << 16);
        const int idx = (n * 64 + k) ^ ((n & 7) << 3);
        *reinterpret_cast<uint2*>(&h_lds[idx]) = make_uint2(lo, hi);
    }
    // ---- adjacency -> 128-bit row masks via ballot ----
    const int* adjb = adj + (size_t)b * NN * NN;
    for (int it = 0; it < 32; ++it) {
        const int idx = wv * 2048 + it * 64 + lane;
        unsigned long long m = __ballot(adjb[idx] != 0);
        if (lane == 0) {
            const int row = idx >> 7, half = (idx >> 6) & 1;
            msk[row * 4 + half * 2]     = (unsigned int)m;
            msk[row * 4 + half * 2 + 1] = (unsigned int)(m >> 32);
        }
    }
    // ---- per-head w staging: wT[o][k] bf16 swizzled ----
    auto stage_w = [&](int hd) {
        const float* wg = w + hd * DIN * DOUT;
        const int o = tid & 63, kb = (tid >> 6) * 8;
        unsigned int u[4];
        #pragma unroll
        for (int p = 0; p < 4; ++p) {
            float f0 = wg[(kb + 2 * p) * DOUT + o];
            float f1 = wg[(kb + 2 * p + 1) * DOUT + o];
            u[p] = f2bf(f0) | ((unsigned int)f2bf(f1) << 16);
        }
        const int idx = (o * 64 + kb) ^ ((o & 7) << 3);
        *reinterpret_cast<uint4*>(&wT[idx]) = make_uint4(u[0], u[1], u[2], u[3]);
    };
    stage_w(0);
    __syncthreads();

    float* outb = out + (size_t)b * HEADS * NN * DOUT;
    const int n0 = wv * 16;

    for (int hd = 0; hd < HEADS; ++hd) {
        // ======== GEMM1: hp[n][o] = sum_i h[n][i] * w[i][o] ========
        floatx4 acc[4] = {floatx4{0,0,0,0}, floatx4{0,0,0,0}, floatx4{0,0,0,0}, floatx4{0,0,0,0}};
        #pragma unroll
        for (int kt = 0; kt < 2; ++kt) {
            const int an = n0 + lm;
            bf16x8 af = ld_frag(&h_lds[(an * 64 + kt * 32 + lg * 8) ^ ((an & 7) << 3)]);
            #pragma unroll
            for (int nt = 0; nt < 4; ++nt) {
                const int o = nt * 16 + lm;
                bf16x8 bfr = ld_frag(&wT[(o * 64 + kt * 32 + lg * 8) ^ ((o & 7) << 3)]);
                acc[nt] = __builtin_amdgcn_mfma_f32_16x16x32_bf16(af, bfr, acc[nt], 0, 0, 0);
            }
        }
        // tanh -> src/dst partial dots; hp -> hpT (bf16, transposed, swizzled)
        const float* asp = a_src + hd * DOUT;
        const float* adp = a_dst + hd * DOUT;
        float ps[4] = {0, 0, 0, 0}, pd[4] = {0, 0, 0, 0};
        #pragma unroll
        for (int nt = 0; nt < 4; ++nt) {
            const int o = nt * 16 + lm;
            const float as = asp[o], ad = adp[o];
            #pragma unroll
            for (int r = 0; r < 4; ++r) {
                const float v = acc[nt][r];
                const float ex = __expf(2.f * v);
                const float t = 1.f - 2.f / (ex + 1.f);   // tanh
                ps[r] = fmaf(t, as, ps[r]);
                pd[r] = fmaf(t, ad, pd[r]);
            }
            const int jb = n0 + lg * 4;
            unsigned int u01 = f2bf(acc[nt][0]) | ((unsigned int)f2bf(acc[nt][1]) << 16);
            unsigned int u23 = f2bf(acc[nt][2]) | ((unsigned int)f2bf(acc[nt][3]) << 16);
            const int base = (o * 128 + jb) ^ ((o & 7) << 3);
            *reinterpret_cast<unsigned int*>(&hpT[base])     = u01;
            *reinterpret_cast<unsigned int*>(&hpT[base + 2]) = u23;
        }
        #pragma unroll
        for (int r = 0; r < 4; ++r) {
            #pragma unroll
            for (int m = 1; m <= 8; m <<= 1) {
                ps[r] += __shfl_xor(ps[r], m);
                pd[r] += __shfl_xor(pd[r], m);
            }
        }
        if (lm == 0) {
            #pragma unroll
            for (int r = 0; r < 4; ++r) {
                s_src[n0 + lg * 4 + r] = ps[r];
                s_dst[n0 + lg * 4 + r] = pd[r];
            }
        }
        __syncthreads();

        // ======== softmax (in-register, A-frag layout) + GEMM2 ========
        if (hd + 1 < HEADS) stage_w(hd + 1);   // overlaps; wT read only after next barrier

        const int i = n0 + lm;   // this lane's softmax row
        uint4 mr = *reinterpret_cast<const uint4*>(&msk[i * 4]);
        const unsigned int mw[4] = {mr.x, mr.y, mr.z, mr.w};
        const float si = s_src[i];

        // pass 1: masked max of raw x (leaky is monotonic -> max first)
        float mx = -3.0e38f;
        #pragma unroll
        for (int kt = 0; kt < 4; ++kt) {
            float4 d0 = *reinterpret_cast<const float4*>(&s_dst[kt * 32 + lg * 8]);
            float4 d1 = *reinterpret_cast<const float4*>(&s_dst[kt * 32 + lg * 8 + 4]);
            const float dv[8] = {d0.x, d0.y, d0.z, d0.w, d1.x, d1.y, d1.z, d1.w};
            #pragma unroll
            for (int q = 0; q < 8; ++q) {
                const bool bit = (mw[kt] >> (lg * 8 + q)) & 1;
                mx = fmaxf(mx, bit ? (si + dv[q]) : -3.0e38f);
            }
        }
        mx = fmaxf(mx, __shfl_xor(mx, 16));
        mx = fmaxf(mx, __shfl_xor(mx, 32));
        const float mxl = fmaxf(mx, 0.f) + 0.2f * fminf(mx, 0.f);  // leaky(mx)

        // pass 2: e = exp(leaky(x)-mxl) -> bf16 A-frags; sum for 1/sum
        float sum = 0.f;
        bf16x8 af2[4];
        #pragma unroll
        for (int kt = 0; kt < 4; ++kt) {
            float4 d0 = *reinterpret_cast<const float4*>(&s_dst[kt * 32 + lg * 8]);
            float4 d1 = *reinterpret_cast<const float4*>(&s_dst[kt * 32 + lg * 8 + 4]);
            const float dv[8] = {d0.x, d0.y, d0.z, d0.w, d1.x, d1.y, d1.z, d1.w};
            bf16x8 a;
            #pragma unroll
            for (int q = 0; q < 8; ++q) {
                const float x = si + dv[q];
                const float xl = fmaxf(x, 0.f) + 0.2f * fminf(x, 0.f);
                const bool bit = (mw[kt] >> (lg * 8 + q)) & 1;
                const float e = __expf((bit ? xl : -3.0e38f) - mxl);
                sum += e;
                a[q] = (__bf16)e;
            }
            af2[kt] = a;
        }
        sum += __shfl_xor(sum, 16);
        sum += __shfl_xor(sum, 32);
        const float inv = 1.f / sum;

        floatx4 oacc[4] = {floatx4{0,0,0,0}, floatx4{0,0,0,0}, floatx4{0,0,0,0}, floatx4{0,0,0,0}};
        #pragma unroll
        for (int kt = 0; kt < 4; ++kt) {
            #pragma unroll
            for (int nt = 0; nt < 4; ++nt) {
                const int o = nt * 16 + lm;
                bf16x8 bfr = ld_frag(&hpT[(o * 128 + kt * 32 + lg * 8) ^ ((o & 7) << 3)]);
                oacc[nt] = __builtin_amdgcn_mfma_f32_16x16x32_bf16(af2[kt], bfr, oacc[nt], 0, 0, 0);
            }
        }
        // normalize rows by 1/sum (row of D = n0+lg*4+r, held by lane lg*4+r in A-phase)
        float invr[4];
        #pragma unroll
        for (int r = 0; r < 4; ++r) invr[r] = __shfl(inv, lg * 4 + r);
        #pragma unroll
        for (int nt = 0; nt < 4; ++nt) {
            const int o = nt * 16 + lm;
            const float bo = bias[o];
            #pragma unroll
            for (int r = 0; r < 4; ++r) {
                const int row = n0 + lg * 4 + r;
                outb[(size_t)hd * NN * DOUT + row * DOUT + o] = fmaf(oacc[nt][r], invr[r], bo);
            }
        }
        __syncthreads();   // protect hpT/s_src/s_dst/wT before next head's writes
    }
}

extern "C" void kernel_launch(void* const* d_in, const int* in_sizes, int n_in,
                              void* d_out, int out_size, void* d_ws, size_t ws_size,
                              hipStream_t stream) {
    (void)in_sizes; (void)n_in; (void)out_size; (void)d_ws; (void)ws_size;
    const float* h     = (const float*)d_in[0];
    const int*   adj   = (const int*)d_in[1];
    const float* w     = (const float*)d_in[2];
    const float* a_src = (const float*)d_in[3];
    const float* a_dst = (const float*)d_in[4];
    const float* bias  = (const float*)d_in[5];
    float* out = (float*)d_out;
    gat_fwd<<<dim3(BSZ), dim3(512), 0, stream>>>(h, adj, w, a_src, a_dst, bias, out);
}

// Round 3
// 66.940 us; speedup vs baseline: 5.8718x; 1.1387x over previous
//
#include <hip/hip_runtime.h>

#define BSZ 512
#define NN 128
#define HEADS 8
#define DIN 64
#define DOUT 64

typedef __bf16 bf16x8 __attribute__((ext_vector_type(8)));
typedef float floatx4 __attribute__((ext_vector_type(4)));

static __device__ __forceinline__ unsigned short f2bf(float f) {
    __bf16 b = (__bf16)f;
    return __builtin_bit_cast(unsigned short, b);
}
static __device__ __forceinline__ bf16x8 ld_frag(const unsigned short* p) {
    uint4 r = *reinterpret_cast<const uint4*>(p);
    return __builtin_bit_cast(bf16x8, r);
}

// one block per batch element b; 512 threads = 8 waves
__global__ __launch_bounds__(512, 4) void gat_fwd(
    const float* __restrict__ hin,    // [BSZ][NN][DIN]
    const int*   __restrict__ adj,    // [BSZ][NN][NN]
    const float* __restrict__ w,      // [HEADS][DIN][DOUT]
    const float* __restrict__ a_src,  // [HEADS][DOUT]
    const float* __restrict__ a_dst,  // [HEADS][DOUT]
    const float* __restrict__ bias,   // [DOUT]
    float* __restrict__ out)          // [BSZ][HEADS][NN][DOUT]
{
    // tiles XOR-swizzled: elem_idx ^= (row&7)<<3  (16B chunk swizzle)
    __shared__ __attribute__((aligned(16))) unsigned short wT[DOUT * DIN];    // 8 KB  [o][k]
    __shared__ __attribute__((aligned(16))) unsigned short hpT[DOUT * NN];    // 16 KB [o][j]
    __shared__ __attribute__((aligned(16))) unsigned short P[NN * NN];        // 32 KB [i][j] bf16 e-vals
    __shared__ __attribute__((aligned(16))) unsigned int   msk[NN * 4];       // 2 KB  row bitmasks
    __shared__ __attribute__((aligned(16))) float s_src[NN];
    __shared__ __attribute__((aligned(16))) float s_dst[NN];

    const int b    = blockIdx.x;
    const int tid  = threadIdx.x;
    const int lane = tid & 63;
    const int wv   = tid >> 6;    // 0..7
    const int lg   = lane >> 4;   // 0..3
    const int lm   = lane & 15;   // 0..15
    const int n0   = wv * 16;

    // ---- h A-fragments: head-invariant, straight to registers ----
    const float* hb = hin + (size_t)b * NN * DIN;
    bf16x8 hA[2];
    #pragma unroll
    for (int kt = 0; kt < 2; ++kt) {
        const float* p = hb + (n0 + lm) * DIN + kt * 32 + lg * 8;
        float4 v0 = *reinterpret_cast<const float4*>(p);
        float4 v1 = *reinterpret_cast<const float4*>(p + 4);
        bf16x8 a;
        a[0] = (__bf16)v0.x; a[1] = (__bf16)v0.y; a[2] = (__bf16)v0.z; a[3] = (__bf16)v0.w;
        a[4] = (__bf16)v1.x; a[5] = (__bf16)v1.y; a[6] = (__bf16)v1.z; a[7] = (__bf16)v1.w;
        hA[kt] = a;
    }

    // ---- adjacency -> 128-bit row masks via ballot ----
    const int* adjb = adj + (size_t)b * NN * NN;
    for (int it = 0; it < 32; ++it) {
        const int idx = wv * 2048 + it * 64 + lane;
        unsigned long long m = __ballot(adjb[idx] != 0);
        if (lane == 0) {
            const int row = idx >> 7, half = (idx >> 6) & 1;
            msk[row * 4 + half * 2]     = (unsigned int)m;
            msk[row * 4 + half * 2 + 1] = (unsigned int)(m >> 32);
        }
    }
    // ---- per-head w staging: wT[o][k] bf16 swizzled ----
    auto stage_w = [&](int hd) {
        const float* wg = w + hd * DIN * DOUT;
        const int o = tid & 63, kb = (tid >> 6) * 8;
        unsigned int u[4];
        #pragma unroll
        for (int p = 0; p < 4; ++p) {
            float f0 = wg[(kb + 2 * p) * DOUT + o];
            float f1 = wg[(kb + 2 * p + 1) * DOUT + o];
            u[p] = f2bf(f0) | ((unsigned int)f2bf(f1) << 16);
        }
        const int idx = (o * 64 + kb) ^ ((o & 7) << 3);
        *reinterpret_cast<uint4*>(&wT[idx]) = make_uint4(u[0], u[1], u[2], u[3]);
    };
    stage_w(0);
    __syncthreads();

    float* outb = out + (size_t)b * HEADS * NN * DOUT;
    float bo[4];
    #pragma unroll
    for (int nt = 0; nt < 4; ++nt) bo[nt] = bias[nt * 16 + lm];

    for (int hd = 0; hd < HEADS; ++hd) {
        // ======== phase 1: GEMM1 + tanh + src/dst reductions ========
        floatx4 acc[4] = {floatx4{0,0,0,0}, floatx4{0,0,0,0}, floatx4{0,0,0,0}, floatx4{0,0,0,0}};
        #pragma unroll
        for (int kt = 0; kt < 2; ++kt) {
            #pragma unroll
            for (int nt = 0; nt < 4; ++nt) {
                const int o = nt * 16 + lm;
                bf16x8 bfr = ld_frag(&wT[(o * 64 + kt * 32 + lg * 8) ^ ((o & 7) << 3)]);
                acc[nt] = __builtin_amdgcn_mfma_f32_16x16x32_bf16(hA[kt], bfr, acc[nt], 0, 0, 0);
            }
        }
        const float* asp = a_src + hd * DOUT;
        const float* adp = a_dst + hd * DOUT;
        float ps[4] = {0, 0, 0, 0}, pd[4] = {0, 0, 0, 0};
        #pragma unroll
        for (int nt = 0; nt < 4; ++nt) {
            const int o = nt * 16 + lm;
            const float as = asp[o], ad = adp[o];
            #pragma unroll
            for (int r = 0; r < 4; ++r) {
                const float v = acc[nt][r];
                const float ex = __expf(2.f * v);
                const float t = 1.f - 2.f / (ex + 1.f);   // tanh, exact formula
                ps[r] = fmaf(t, as, ps[r]);
                pd[r] = fmaf(t, ad, pd[r]);
            }
            const int jb = n0 + lg * 4;
            unsigned int u01 = f2bf(acc[nt][0]) | ((unsigned int)f2bf(acc[nt][1]) << 16);
            unsigned int u23 = f2bf(acc[nt][2]) | ((unsigned int)f2bf(acc[nt][3]) << 16);
            const int base = (o * 128 + jb) ^ ((o & 7) << 3);
            *reinterpret_cast<unsigned int*>(&hpT[base])     = u01;
            *reinterpret_cast<unsigned int*>(&hpT[base + 2]) = u23;
        }
        #pragma unroll
        for (int r = 0; r < 4; ++r) {
            #pragma unroll
            for (int m = 1; m <= 8; m <<= 1) {
                ps[r] += __shfl_xor(ps[r], m);
                pd[r] += __shfl_xor(pd[r], m);
            }
        }
        if (lm == 0) {
            #pragma unroll
            for (int r = 0; r < 4; ++r) {
                s_src[n0 + lg * 4 + r] = ps[r];
                s_dst[n0 + lg * 4 + r] = pd[r];
            }
        }
        __syncthreads();

        // ======== phase 2: sparse max-free softmax + GEMM2 ========
        if (hd + 1 < HEADS) stage_w(hd + 1);   // wT read only after next barrier

        const int i = n0 + lm;                 // this lane's row (4 lanes/row, lg = j-word)
        const int sw = (i & 7) << 3;
        const float si = s_src[i];

        // zero my 32-col segment of P (4x 16B, swizzled chunks)
        const int pz = i * 128 + lg * 32;
        #pragma unroll
        for (int t = 0; t < 4; ++t)
            *reinterpret_cast<uint4*>(&P[(pz + 8 * t) ^ sw]) = make_uint4(0, 0, 0, 0);

        // bit-scan scatter: only ~6% of entries are unmasked
        unsigned int m = msk[i * 4 + lg];
        float sum = 0.f;
        while (m) {
            const int q = __builtin_ctz(m); m &= m - 1;
            const float x = si + s_dst[lg * 32 + q];
            const float xl = fmaxf(x, 0.f) + 0.2f * fminf(x, 0.f);  // leaky
            const float e = __expf(xl);                              // max-free: x bounded
            const __bf16 eb = (__bf16)e;
            sum += (float)eb;                                        // sum of quantized e
            P[(pz + q) ^ sw] = __builtin_bit_cast(unsigned short, eb);
        }
        sum += __shfl_xor(sum, 16);
        sum += __shfl_xor(sum, 32);
        const float inv = 1.f / sum;

        floatx4 oacc[4] = {floatx4{0,0,0,0}, floatx4{0,0,0,0}, floatx4{0,0,0,0}, floatx4{0,0,0,0}};
        #pragma unroll
        for (int kt = 0; kt < 4; ++kt) {
            const bf16x8 af = ld_frag(&P[(i * 128 + kt * 32 + lg * 8) ^ sw]);
            #pragma unroll
            for (int nt = 0; nt < 4; ++nt) {
                const int o = nt * 16 + lm;
                bf16x8 bfr = ld_frag(&hpT[(o * 128 + kt * 32 + lg * 8) ^ ((o & 7) << 3)]);
                oacc[nt] = __builtin_amdgcn_mfma_f32_16x16x32_bf16(af, bfr, oacc[nt], 0, 0, 0);
            }
        }
        float invr[4];
        #pragma unroll
        for (int r = 0; r < 4; ++r) invr[r] = __shfl(inv, lg * 4 + r);
        #pragma unroll
        for (int nt = 0; nt < 4; ++nt) {
            const int o = nt * 16 + lm;
            #pragma unroll
            for (int r = 0; r < 4; ++r) {
                const int row = n0 + lg * 4 + r;
                outb[(size_t)hd * NN * DOUT + row * DOUT + o] = fmaf(oacc[nt][r], invr[r], bo[nt]);
            }
        }
        __syncthreads();   // hpT/s_src/s_dst reads done before next head overwrites
    }
}

extern "C" void kernel_launch(void* const* d_in, const int* in_sizes, int n_in,
                              void* d_out, int out_size, void* d_ws, size_t ws_size,
                              hipStream_t stream) {
    (void)in_sizes; (void)n_in; (void)out_size; (void)d_ws; (void)ws_size;
    const float* h     = (const float*)d_in[0];
    const int*   adj   = (const int*)d_in[1];
    const float* w     = (const float*)d_in[2];
    const float* a_src = (const float*)d_in[3];
    const float* a_dst = (const float*)d_in[4];
    const float* bias  = (const float*)d_in[5];
    float* out = (float*)d_out;
    gat_fwd<<<dim3(BSZ), dim3(512), 0, stream>>>(h, adj, w, a_src, a_dst, bias, out);
}